// Round 2
// baseline (366.315 us; speedup 1.0000x reference)
//
#include <hip/hip_runtime.h>
#include <hip/hip_fp16.h>

#define NN 50000   // nodes
#define NE 800000  // edges
#define NH 128     // hidden
#define NG 32      // graphs
#define NL 4       // layers
#define NB 196     // ceil(NN/256)
#define PREPB 320  // ceil(5*WSLOT/256)
#define HISTB 3125 // ceil(NE/256)
#define WSLOT (NH * NH)  // 16384 elements per weight slot

typedef __attribute__((ext_vector_type(8))) short bf16x8;
typedef __attribute__((ext_vector_type(4))) float f32x4;
typedef __attribute__((ext_vector_type(2))) float f32x2;

__device__ inline short f2bf(float x) {
  union { float f; unsigned u; } v;
  v.f = x;
  unsigned r = v.u + 0x7FFF + ((v.u >> 16) & 1);
  return (short)(r >> 16);
}
__device__ inline float bf2f(short s) {
  union { unsigned u; float f; } v;
  v.u = ((unsigned)(unsigned short)s) << 16;
  return v.f;
}

// permuted fp8-trunk layout: channel ch=(ks*32 + q*8 + j) stored at byte
// q*32 + ks*8 + j  -> each MFMA lane (quad) reads its 32 channels as 2x uint4.
// epilogue writes channels ch = t*16 + quad*4 + r; their dword index in the
// permuted row is:
__device__ inline int pdw(int t, int quad) {
  return (((2 * t + (quad >> 1)) & 3) << 3) + ((t >> 1) << 1) + (quad & 1);
}

// accumulate one fp8 row slice (2x uint4 = lane's 32 channels) into ag, * w
__device__ inline void fp8row_fma(float (&ag)[4][8], uint4 qa, uint4 qb,
                                  float w) {
  const unsigned dw[8] = {qa.x, qa.y, qa.z, qa.w, qb.x, qb.y, qb.z, qb.w};
#pragma unroll
  for (int ks = 0; ks < 4; ++ks) {
    f32x2 u0 = __builtin_amdgcn_cvt_pk_f32_fp8(dw[2 * ks], 0);
    f32x2 u1 = __builtin_amdgcn_cvt_pk_f32_fp8(dw[2 * ks], 1);
    f32x2 u2 = __builtin_amdgcn_cvt_pk_f32_fp8(dw[2 * ks + 1], 0);
    f32x2 u3 = __builtin_amdgcn_cvt_pk_f32_fp8(dw[2 * ks + 1], 1);
    ag[ks][0] += u0.x * w; ag[ks][1] += u0.y * w;
    ag[ks][2] += u1.x * w; ag[ks][3] += u1.y * w;
    ag[ks][4] += u2.x * w; ag[ks][5] += u2.y * w;
    ag[ks][6] += u3.x * w; ag[ks][7] += u3.y * w;
  }
}

// 256-thread block exclusive scan (wave shuffle + 4-wave combine)
__device__ inline int block_exscan(int v) {
  __shared__ int wsum[4];
  int tid = threadIdx.x, wave = tid >> 6, lane = tid & 63;
  int x = v;
#pragma unroll
  for (int off = 1; off < 64; off <<= 1) {
    int y = __shfl_up(x, off, 64);
    if (lane >= off) x += y;
  }
  if (lane == 63) wsum[wave] = x;
  __syncthreads();
  int wp = 0;
  if (wave > 0) wp += wsum[0];
  if (wave > 1) wp += wsum[1];
  if (wave > 2) wp += wsum[2];
  return wp + x - v;
}

// ---------------- fused: W split/swizzle (blocks 0..319) + degree hist -------
// frag layout: idx = ((ks*8 + t)*64 + lane)*8 + j  <->  W[n][k],
//   n = t*16 + (lane&15), k = ks*32 + (lane>>4)*8 + j
__global__ __launch_bounds__(256) void prep_hist_kernel(
    const float* __restrict__ W_emb, const float* __restrict__ W_layers,
    short* __restrict__ hi, short* __restrict__ lo, const int* __restrict__ col,
    int* __restrict__ cnt, int* __restrict__ rank) {
  if (blockIdx.x < PREPB) {
    int i = blockIdx.x * 256 + threadIdx.x;
    if (i >= 5 * WSLOT) return;
    int slot = i >> 14, f = i & (WSLOT - 1);
    int j = f & 7, lane = (f >> 3) & 63, tt = (f >> 9) & 7, ks = f >> 12;
    int n = tt * 16 + (lane & 15);
    int k = ks * 32 + ((lane >> 4) & 3) * 8 + j;
    const float* W = slot ? (W_layers + (size_t)(slot - 1) * WSLOT) : W_emb;
    float x = W[n * NH + k];
    short hh = f2bf(x);
    hi[i] = hh;
    lo[i] = f2bf(x - bf2f(hh));
  } else {
    int e = (blockIdx.x - PREPB) * 256 + threadIdx.x;
    if (e < NE) rank[e] = atomicAdd(&cnt[col[e]], 1);
  }
}

// ---------------- scan stage 1: per-block sum of cnt, plus dis ----------------
__global__ __launch_bounds__(256) void scan1_kernel(const int* __restrict__ cnt,
                                                    int* __restrict__ bsum,
                                                    float* __restrict__ dis) {
  int i = blockIdx.x * 256 + threadIdx.x;
  int v = (i < NN) ? cnt[i] : 0;
  if (i < NN) dis[i] = rsqrtf((float)(v + 1));
  int lane = threadIdx.x & 63;
  int s = v;
#pragma unroll
  for (int off = 32; off; off >>= 1) s += __shfl_down(s, off, 64);
  __shared__ int ws[4];
  if (lane == 0) ws[threadIdx.x >> 6] = s;
  __syncthreads();
  if (threadIdx.x == 0) bsum[blockIdx.x] = ws[0] + ws[1] + ws[2] + ws[3];
}

// ---------------- scan stage 2+3 fused: each block redundantly reduces the
// 196 block sums (masked to i < blockIdx) for its offset, then local scan.
__global__ __launch_bounds__(256) void scan3b_kernel(const int* __restrict__ cnt,
                                                     const int* __restrict__ bsum,
                                                     int* __restrict__ offs) {
  __shared__ int ws2[4];
  int tid = threadIdx.x;
  int b = blockIdx.x;
  int v = (tid < NB && tid < b) ? bsum[tid] : 0;
  int lane = tid & 63;
  int s = v;
#pragma unroll
  for (int off = 32; off; off >>= 1) s += __shfl_down(s, off, 64);
  if (lane == 0) ws2[tid >> 6] = s;
  __syncthreads();
  int bo = ws2[0] + ws2[1] + ws2[2] + ws2[3];
  int i = b * 256 + tid;
  int c = (i < NN) ? cnt[i] : 0;
  int ex = block_exscan(c);
  if (i < NN) offs[i] = bo + ex;
}

// ---------------- CSR fill (no atomics: rank precomputed by hist) ------------
__global__ __launch_bounds__(256) void fill_kernel(const int* __restrict__ row,
                                                   const int* __restrict__ col,
                                                   const int* __restrict__ rank,
                                                   const float* __restrict__ dis,
                                                   const int* __restrict__ offs,
                                                   int2* __restrict__ csr) {
  int e = blockIdx.x * 256 + threadIdx.x;
  if (e < NE) {
    int d = col[e];
    int s = row[e];
    int pos = offs[d] + rank[e];
    csr[pos] = make_int2(s, __float_as_int(dis[s] * dis[d]));
  }
}

// ---------------- embedding GEMM: h0 = x @ W_emb^T + b, fp16 + fp8(perm) -----
__global__ __launch_bounds__(512) void emb_gemm(const float* __restrict__ Xf,
                                                const short* __restrict__ Whi,
                                                const short* __restrict__ Wlo,
                                                const float* __restrict__ bias,
                                                __half* __restrict__ hnew,
                                                unsigned char* __restrict__ h8) {
  __shared__ short Wh[WSLOT];  // 32 KB
  __shared__ short Wl[WSLOT];  // 32 KB
  int tid = threadIdx.x;
#pragma unroll
  for (int i = tid * 8; i < WSLOT; i += 512 * 8) {
    *(bf16x8*)&Wh[i] = *(const bf16x8*)(Whi + i);
    *(bf16x8*)&Wl[i] = *(const bf16x8*)(Wlo + i);
  }
  __syncthreads();

  int wave = tid >> 6, lane = tid & 63;
  int quad = lane >> 4, r16 = lane & 15;
  int m0 = blockIdx.x * 128 + wave * 16;
  if (m0 >= NN) return;  // NN % 16 == 0
  int mA = m0 + r16;

  f32x4 acc[8];
#pragma unroll
  for (int t = 0; t < 8; ++t) acc[t] = (f32x4){0.f, 0.f, 0.f, 0.f};

#pragma unroll
  for (int ks = 0; ks < 4; ++ks) {
    int klane = ks * 32 + quad * 8;
    const float* xr = Xf + (size_t)mA * NH + klane;
    float4 a0 = *(const float4*)xr;
    float4 a1 = *(const float4*)(xr + 4);
    float af[8] = {a0.x, a0.y, a0.z, a0.w, a1.x, a1.y, a1.z, a1.w};
    bf16x8 xhi, xlo;
#pragma unroll
    for (int j = 0; j < 8; ++j) {
      short h = f2bf(af[j]);
      xhi[j] = h;
      xlo[j] = f2bf(af[j] - bf2f(h));
    }
#pragma unroll
    for (int t = 0; t < 8; ++t) {
      int fidx = ((ks * 8 + t) * 64 + lane) << 3;
      bf16x8 whi = *(const bf16x8*)&Wh[fidx];
      bf16x8 wlo = *(const bf16x8*)&Wl[fidx];
      acc[t] = __builtin_amdgcn_mfma_f32_16x16x32_bf16(whi, xhi, acc[t], 0, 0, 0);
      acc[t] = __builtin_amdgcn_mfma_f32_16x16x32_bf16(whi, xlo, acc[t], 0, 0, 0);
      acc[t] = __builtin_amdgcn_mfma_f32_16x16x32_bf16(wlo, xhi, acc[t], 0, 0, 0);
    }
  }

  int m = m0 + r16;
  int cb = quad * 4;
#pragma unroll
  for (int t = 0; t < 8; ++t) {
    int ch = t * 16 + cb;
    float4 bb = *(const float4*)(bias + ch);
    float o0 = acc[t][0] + bb.x, o1 = acc[t][1] + bb.y;
    float o2 = acc[t][2] + bb.z, o3 = acc[t][3] + bb.w;
    __half2 p01 = __float22half2_rn(make_float2(o0, o1));
    __half2 p23 = __float22half2_rn(make_float2(o2, o3));
    *(uint2*)(hnew + (size_t)m * NH + ch) =
        make_uint2(*(unsigned*)&p01, *(unsigned*)&p23);
    int v = 0;
    v = __builtin_amdgcn_cvt_pk_fp8_f32(o0, o1, v, 0);
    v = __builtin_amdgcn_cvt_pk_fp8_f32(o2, o3, v, 1);
    ((unsigned*)(h8 + (size_t)m * NH))[pdw(t, quad)] = (unsigned)v;
  }
}

// ---------------- fused layer: gather (A_hat . h, fp8 trunk) -> registers ->
// split-bf16 MFMA (W in LDS) -> bias+relu+residual+LN epilogue.
// Gather is batched 4 edges wide with software-pipelined CSR prefetch:
// per batch, 8 independent row loads are in flight while the next batch's
// 4 csr entries load. In-batch tail slots use a dummy (self node, weight 0)
// whose row is L1-hot. h8 double-buffered (reads l-1 while writing l).
template <bool LAST>
__global__ __launch_bounds__(512) void layer_fused(
    const unsigned char* __restrict__ h8in, const short* __restrict__ Whi,
    const short* __restrict__ Wlo, const float* __restrict__ bias,
    const __half* __restrict__ hprev, const float* __restrict__ gamma,
    const float* __restrict__ beta, const float* __restrict__ Wout,
    const float* __restrict__ dis, const int* __restrict__ offs,
    const int* __restrict__ cnt, const int2* __restrict__ csr,
    __half* __restrict__ hnew, unsigned char* __restrict__ h8out,
    float* __restrict__ nodeval) {
  __shared__ short Wh[WSLOT];  // 32 KB
  __shared__ short Wl[WSLOT];  // 32 KB
  int tid = threadIdx.x;
#pragma unroll
  for (int i = tid * 8; i < WSLOT; i += 512 * 8) {
    *(bf16x8*)&Wh[i] = *(const bf16x8*)(Whi + i);
    *(bf16x8*)&Wl[i] = *(const bf16x8*)(Wlo + i);
  }
  // no barrier yet: gather overlaps the LDS staging latency

  int wave = tid >> 6, lane = tid & 63;
  int quad = lane >> 4, r16 = lane & 15;
  int m0 = blockIdx.x * 128 + wave * 16;
  bool active = m0 < NN;        // wave-uniform; inactive waves still barrier
  int nd = active ? m0 + r16 : 0;

  float ag[4][8];
#pragma unroll
  for (int ks = 0; ks < 4; ++ks)
#pragma unroll
    for (int j = 0; j < 8; ++j) ag[ks][j] = 0.f;

  const char* rbase = (const char*)h8in + quad * 32;
  {  // self loop: weight dis[nd]^2
    float dii = dis[nd];
    const uint4* rp = (const uint4*)(rbase + (size_t)nd * NH);
    uint4 qa = rp[0], qb = rp[1];
    fp8row_fma(ag, qa, qb, dii * dii);
  }
  int s0 = offs[nd];
  int e = active ? cnt[nd] : 0;
  const int2 self2 = make_int2(nd, 0);
  int nbat = (e + 3) >> 2;
  int2 p0 = self2, p1 = self2, p2 = self2, p3 = self2;
  if (e > 0) p0 = csr[s0 + 0];
  if (e > 1) p1 = csr[s0 + 1];
  if (e > 2) p2 = csr[s0 + 2];
  if (e > 3) p3 = csr[s0 + 3];
  for (int b = 0; b < nbat; ++b) {
    const uint4* r0 = (const uint4*)(rbase + (size_t)p0.x * NH);
    const uint4* r1 = (const uint4*)(rbase + (size_t)p1.x * NH);
    const uint4* r2 = (const uint4*)(rbase + (size_t)p2.x * NH);
    const uint4* r3 = (const uint4*)(rbase + (size_t)p3.x * NH);
    uint4 a0 = r0[0], b0 = r0[1];
    uint4 a1 = r1[0], b1 = r1[1];
    uint4 a2 = r2[0], b2 = r2[1];
    uint4 a3 = r3[0], b3 = r3[1];
    float w0 = __int_as_float(p0.y), w1 = __int_as_float(p1.y);
    float w2 = __int_as_float(p2.y), w3 = __int_as_float(p3.y);
    // prefetch next batch's csr while rows are in flight
    int nxt = (b + 1) << 2;
    int base = s0 + nxt, rem = e - nxt;
    p0 = (rem > 0) ? csr[base + 0] : self2;
    p1 = (rem > 1) ? csr[base + 1] : self2;
    p2 = (rem > 2) ? csr[base + 2] : self2;
    p3 = (rem > 3) ? csr[base + 3] : self2;
    fp8row_fma(ag, a0, b0, w0);
    fp8row_fma(ag, a1, b1, w1);
    fp8row_fma(ag, a2, b2, w2);
    fp8row_fma(ag, a3, b3, w3);
  }

  __syncthreads();  // W staging complete; all waves participate

  if (!active) return;

  f32x4 acc[8];
#pragma unroll
  for (int t = 0; t < 8; ++t) acc[t] = (f32x4){0.f, 0.f, 0.f, 0.f};

#pragma unroll
  for (int ks = 0; ks < 4; ++ks) {
    bf16x8 xhi, xlo;
#pragma unroll
    for (int q = 0; q < 8; ++q) {
      short hh = f2bf(ag[ks][q]);
      xhi[q] = hh;
      xlo[q] = f2bf(ag[ks][q] - bf2f(hh));
    }
#pragma unroll
    for (int t = 0; t < 8; ++t) {
      int fidx = ((ks * 8 + t) * 64 + lane) << 3;
      bf16x8 whi = *(const bf16x8*)&Wh[fidx];
      bf16x8 wlo = *(const bf16x8*)&Wl[fidx];
      acc[t] = __builtin_amdgcn_mfma_f32_16x16x32_bf16(whi, xhi, acc[t], 0, 0, 0);
      acc[t] = __builtin_amdgcn_mfma_f32_16x16x32_bf16(whi, xlo, acc[t], 0, 0, 0);
      acc[t] = __builtin_amdgcn_mfma_f32_16x16x32_bf16(wlo, xhi, acc[t], 0, 0, 0);
    }
  }

  // ---- epilogue: lane owns node m = m0 + r16, channels ch = t*16 + quad*4 + r
  int m = m0 + r16;
  int cb = quad * 4;
  float vv[8][4];
  float s = 0.f, s2 = 0.f;
#pragma unroll
  for (int t = 0; t < 8; ++t) {
    int ch = t * 16 + cb;
    float4 bb = *(const float4*)(bias + ch);
    uint2 hp = *(const uint2*)(hprev + (size_t)m * NH + ch);
    float2 h01 = __half22float2(*(__half2*)&hp.x);
    float2 h23 = __half22float2(*(__half2*)&hp.y);
    float hv[4] = {h01.x, h01.y, h23.x, h23.y};
    float bb4[4] = {bb.x, bb.y, bb.z, bb.w};
#pragma unroll
    for (int r = 0; r < 4; ++r) {
      float z = fmaxf(acc[t][r] + bb4[r], 0.f);
      float val = hv[r] + z;
      vv[t][r] = val;
      s += val;
      s2 += val * val;
    }
  }
  // reduce across the 4 quads holding this node
  s += __shfl_xor(s, 16, 64);
  s += __shfl_xor(s, 32, 64);
  s2 += __shfl_xor(s2, 16, 64);
  s2 += __shfl_xor(s2, 32, 64);
  float mean = s * (1.f / 128.f);
  float var = fmaxf(s2 * (1.f / 128.f) - mean * mean, 0.f);
  float inv = rsqrtf(var + 1e-5f);
  float d = 0.f;
#pragma unroll
  for (int t = 0; t < 8; ++t) {
    int ch = t * 16 + cb;
    float4 gv = *(const float4*)(gamma + ch);
    float4 bt = *(const float4*)(beta + ch);
    float o0 = (vv[t][0] - mean) * inv * gv.x + bt.x;
    float o1 = (vv[t][1] - mean) * inv * gv.y + bt.y;
    float o2 = (vv[t][2] - mean) * inv * gv.z + bt.z;
    float o3 = (vv[t][3] - mean) * inv * gv.w + bt.w;
    if (!LAST) {
      __half2 p01 = __float22half2_rn(make_float2(o0, o1));
      __half2 p23 = __float22half2_rn(make_float2(o2, o3));
      *(uint2*)(hnew + (size_t)m * NH + ch) =
          make_uint2(*(unsigned*)&p01, *(unsigned*)&p23);
      int pv = 0;
      pv = __builtin_amdgcn_cvt_pk_fp8_f32(o0, o1, pv, 0);
      pv = __builtin_amdgcn_cvt_pk_fp8_f32(o2, o3, pv, 1);
      ((unsigned*)(h8out + (size_t)m * NH))[pdw(t, quad)] = (unsigned)pv;
    } else {
      // last layer: nothing reads h/h8 afterwards; only nodeval matters
      float4 wv = *(const float4*)(Wout + ch);
      d += o0 * wv.x + o1 * wv.y + o2 * wv.z + o3 * wv.w;
    }
  }
  if (LAST) {
    d += __shfl_xor(d, 16, 64);
    d += __shfl_xor(d, 32, 64);
    if (lane < 16) nodeval[m] = d;
  }
}

// ---------------- LDS-binned segment reduction + last-block finalize ----------
__global__ __launch_bounds__(256) void reduce_pool_kernel(
    const float* __restrict__ nodeval, const int* __restrict__ batch,
    float* __restrict__ gsum, int* __restrict__ gcnt, int* __restrict__ done,
    float* __restrict__ out) {
  __shared__ float bins[NG];
  __shared__ int cbins[NG];
  __shared__ int lastflag;
  int tid = threadIdx.x;
  if (tid < NG) {
    bins[tid] = 0.f;
    cbins[tid] = 0;
  }
  __syncthreads();
  int i = blockIdx.x * 256 + tid;
  if (i < NN) {
    int g = batch[i];
    atomicAdd(&bins[g], nodeval[i]);
    atomicAdd(&cbins[g], 1);
  }
  __syncthreads();
  if (tid < NG && cbins[tid]) {
    atomicAdd(&gsum[tid], bins[tid]);
    atomicAdd(&gcnt[tid], cbins[tid]);
  }
  __threadfence();
  if (tid == 0) lastflag = (atomicAdd(done, 1) == (int)gridDim.x - 1);
  __syncthreads();
  if (lastflag && tid < NG) {
    // atomic reads: guaranteed to observe all prior device-scope atomics
    float sv = atomicAdd(&gsum[tid], 0.f);
    int cv = atomicAdd(&gcnt[tid], 0);
    out[tid] = sv / fmaxf((float)cv, 1.0f);
  }
}

extern "C" void kernel_launch(void* const* d_in, const int* in_sizes, int n_in,
                              void* d_out, int out_size, void* d_ws, size_t ws_size,
                              hipStream_t stream) {
  const float* x = (const float*)d_in[0];
  const int* eidx = (const int*)d_in[1];
  const int* batch = (const int*)d_in[2];
  const float* W_emb = (const float*)d_in[3];
  const float* b_emb = (const float*)d_in[4];
  const float* W_layers = (const float*)d_in[5];
  const float* b_layers = (const float*)d_in[6];
  const float* ln_gamma = (const float*)d_in[7];
  const float* ln_beta = (const float*)d_in[8];
  const float* W_out = (const float*)d_in[9];
  float* out = (float*)d_out;

  char* ws = (char*)d_ws;
  unsigned char* h8a = (unsigned char*)ws; ws += (size_t)NN * NH;  // fp8 trunk A
  unsigned char* h8b = (unsigned char*)ws; ws += (size_t)NN * NH;  // fp8 trunk B
  __half* h = (__half*)ws;      ws += (size_t)NN * NH * 2;         // fp16 trunk
  short* Whi = (short*)ws;      ws += (size_t)5 * WSLOT * 2;
  short* Wlo = (short*)ws;      ws += (size_t)5 * WSLOT * 2;
  float* dis = (float*)ws;      ws += (size_t)NN * 4;
  int2* csr = (int2*)ws;        ws += (size_t)NE * 8;
  int* rank = (int*)ws;         ws += (size_t)NE * 4;
  int* offs = (int*)ws;         ws += (size_t)NN * 4;
  float* nodeval = (float*)ws;  ws += (size_t)NN * 4;
  int* bsum = (int*)ws;         ws += (size_t)NB * 4;
  char* zero_base = ws;
  int* cnt = (int*)ws;          ws += (size_t)NN * 4;
  float* gsum = (float*)ws;     ws += (size_t)NG * 4;
  int* gcnt = (int*)ws;         ws += (size_t)NG * 4;
  int* done = (int*)ws;         ws += 64;
  size_t zero_bytes = (size_t)(ws - zero_base);
  hipMemsetAsync(zero_base, 0, zero_bytes, stream);

  const int* erow = eidx;        // edge_index[0] = sources
  const int* ecol = eidx + NE;   // edge_index[1] = targets

  prep_hist_kernel<<<PREPB + HISTB, 256, 0, stream>>>(W_emb, W_layers, Whi, Wlo,
                                                      ecol, cnt, rank);
  scan1_kernel<<<NB, 256, 0, stream>>>(cnt, bsum, dis);
  scan3b_kernel<<<NB, 256, 0, stream>>>(cnt, bsum, offs);
  fill_kernel<<<HISTB, 256, 0, stream>>>(erow, ecol, rank, dis, offs, csr);

  int gblk = (NN + 127) / 128;
  // embedding: h0 = x @ W_emb^T + b_emb  -> h (fp16) + h8a (fp8, permuted)
  emb_gemm<<<gblk, 512, 0, stream>>>(x, Whi, Wlo, b_emb, h, h8a);
  for (int l = 0; l < NL; ++l) {
    const short* wh = Whi + (size_t)(l + 1) * WSLOT;
    const short* wl = Wlo + (size_t)(l + 1) * WSLOT;
    const float* bl = b_layers + (size_t)l * NH;
    const float* gl = ln_gamma + (size_t)l * NH;
    const float* be = ln_beta + (size_t)l * NH;
    const unsigned char* hin = (l & 1) ? h8b : h8a;
    unsigned char* hout = (l & 1) ? h8a : h8b;
    if (l == NL - 1)
      layer_fused<true><<<gblk, 512, 0, stream>>>(
          hin, wh, wl, bl, h, gl, be, W_out, dis, offs, cnt, csr, h, nullptr,
          nodeval);
    else
      layer_fused<false><<<gblk, 512, 0, stream>>>(
          hin, wh, wl, bl, h, gl, be, nullptr, dis, offs, cnt, csr, h, hout,
          nullptr);
  }
  reduce_pool_kernel<<<NB, 256, 0, stream>>>(nodeval, batch, gsum, gcnt, done,
                                             out);
}

// Round 3
// 327.136 us; speedup vs baseline: 1.1198x; 1.1198x over previous
//
#include <hip/hip_runtime.h>
#include <hip/hip_fp16.h>

#define NN 50000   // nodes
#define NE 800000  // edges
#define NH 128     // hidden
#define NG 32      // graphs
#define NL 4       // layers
#define NB 196     // ceil(NN/256)
#define PREPB 320  // ceil(5*WSLOT/256)
#define HISTB 3125 // ceil(NE/256)
#define NTILE 12500 // source-tile width (4 tiles, 1.6 MB of fp8 trunk each)
#define WSLOT (NH * NH)  // 16384 elements per weight slot

typedef __attribute__((ext_vector_type(8))) short bf16x8;
typedef __attribute__((ext_vector_type(4))) float f32x4;
typedef __attribute__((ext_vector_type(2))) float f32x2;

__device__ inline short f2bf(float x) {
  union { float f; unsigned u; } v;
  v.f = x;
  unsigned r = v.u + 0x7FFF + ((v.u >> 16) & 1);
  return (short)(r >> 16);
}
__device__ inline float bf2f(short s) {
  union { unsigned u; float f; } v;
  v.u = ((unsigned)(unsigned short)s) << 16;
  return v.f;
}

// permuted fp8-trunk layout: channel ch=(ks*32 + q*8 + j) stored at byte
// q*32 + ks*8 + j  -> each MFMA lane (quad) reads its 32 channels as 2x uint4.
// epilogue writes channels ch = t*16 + quad*4 + r; their dword index in the
// permuted row is:
__device__ inline int pdw(int t, int quad) {
  return (((2 * t + (quad >> 1)) & 3) << 3) + ((t >> 1) << 1) + (quad & 1);
}

// accumulate one fp8 row slice (2x uint4 = lane's 32 channels) into ag, * w
__device__ inline void fp8row_fma(float (&ag)[4][8], uint4 qa, uint4 qb,
                                  float w) {
  const unsigned dw[8] = {qa.x, qa.y, qa.z, qa.w, qb.x, qb.y, qb.z, qb.w};
#pragma unroll
  for (int ks = 0; ks < 4; ++ks) {
    f32x2 u0 = __builtin_amdgcn_cvt_pk_f32_fp8(dw[2 * ks], 0);
    f32x2 u1 = __builtin_amdgcn_cvt_pk_f32_fp8(dw[2 * ks], 1);
    f32x2 u2 = __builtin_amdgcn_cvt_pk_f32_fp8(dw[2 * ks + 1], 0);
    f32x2 u3 = __builtin_amdgcn_cvt_pk_f32_fp8(dw[2 * ks + 1], 1);
    ag[ks][0] += u0.x * w; ag[ks][1] += u0.y * w;
    ag[ks][2] += u1.x * w; ag[ks][3] += u1.y * w;
    ag[ks][4] += u2.x * w; ag[ks][5] += u2.y * w;
    ag[ks][6] += u3.x * w; ag[ks][7] += u3.y * w;
  }
}

// 256-thread block exclusive scan (wave shuffle + 4-wave combine)
__device__ inline int block_exscan(int v) {
  __shared__ int wsum[4];
  int tid = threadIdx.x, wave = tid >> 6, lane = tid & 63;
  int x = v;
#pragma unroll
  for (int off = 1; off < 64; off <<= 1) {
    int y = __shfl_up(x, off, 64);
    if (lane >= off) x += y;
  }
  if (lane == 63) wsum[wave] = x;
  __syncthreads();
  int wp = 0;
  if (wave > 0) wp += wsum[0];
  if (wave > 1) wp += wsum[1];
  if (wave > 2) wp += wsum[2];
  return wp + x - v;
}

// ---------------- fused: W split/swizzle (blocks 0..319) + degree hist -------
// hist counts per (target, source-tile): cnt4[d*4 + s/NTILE]; rank is the
// edge's order within its (target,tile) bucket -> CSR becomes tile-grouped,
// which keeps the device-wide gather working set ~1.6 MB (L2-resident).
__global__ __launch_bounds__(256) void prep_hist_kernel(
    const float* __restrict__ W_emb, const float* __restrict__ W_layers,
    short* __restrict__ hi, short* __restrict__ lo, const int* __restrict__ row,
    const int* __restrict__ col, int* __restrict__ cnt4,
    int* __restrict__ rank) {
  if (blockIdx.x < PREPB) {
    int i = blockIdx.x * 256 + threadIdx.x;
    if (i >= 5 * WSLOT) return;
    int slot = i >> 14, f = i & (WSLOT - 1);
    int j = f & 7, lane = (f >> 3) & 63, tt = (f >> 9) & 7, ks = f >> 12;
    int n = tt * 16 + (lane & 15);
    int k = ks * 32 + ((lane >> 4) & 3) * 8 + j;
    const float* W = slot ? (W_layers + (size_t)(slot - 1) * WSLOT) : W_emb;
    float x = W[n * NH + k];
    short hh = f2bf(x);
    hi[i] = hh;
    lo[i] = f2bf(x - bf2f(hh));
  } else {
    int e = (blockIdx.x - PREPB) * 256 + threadIdx.x;
    if (e < NE) {
      int s = row[e];
      int t = s / NTILE;  // 0..3
      rank[e] = atomicAdd(&cnt4[col[e] * 4 + t], 1);
    }
  }
}

// ---------------- scan stage 1: per-block sum of deg, plus dis/deg -----------
__global__ __launch_bounds__(256) void scan1_kernel(const int* __restrict__ cnt4,
                                                    int* __restrict__ bsum,
                                                    float* __restrict__ dis,
                                                    int* __restrict__ deg) {
  int i = blockIdx.x * 256 + threadIdx.x;
  int v = 0;
  if (i < NN) {
    int4 c4 = *(const int4*)&cnt4[i * 4];
    v = c4.x + c4.y + c4.z + c4.w;
    deg[i] = v;
    dis[i] = rsqrtf((float)(v + 1));
  }
  int lane = threadIdx.x & 63;
  int s = v;
#pragma unroll
  for (int off = 32; off; off >>= 1) s += __shfl_down(s, off, 64);
  __shared__ int ws[4];
  if (lane == 0) ws[threadIdx.x >> 6] = s;
  __syncthreads();
  if (threadIdx.x == 0) bsum[blockIdx.x] = ws[0] + ws[1] + ws[2] + ws[3];
}

// ---------------- scan stage 2+3 fused: each block redundantly reduces the
// 196 block sums (masked to i < blockIdx) for its offset, then local scan.
__global__ __launch_bounds__(256) void scan3b_kernel(const int* __restrict__ deg,
                                                     const int* __restrict__ bsum,
                                                     int* __restrict__ offs) {
  __shared__ int ws2[4];
  int tid = threadIdx.x;
  int b = blockIdx.x;
  int v = (tid < NB && tid < b) ? bsum[tid] : 0;
  int lane = tid & 63;
  int s = v;
#pragma unroll
  for (int off = 32; off; off >>= 1) s += __shfl_down(s, off, 64);
  if (lane == 0) ws2[tid >> 6] = s;
  __syncthreads();
  int bo = ws2[0] + ws2[1] + ws2[2] + ws2[3];
  int i = b * 256 + tid;
  int c = (i < NN) ? deg[i] : 0;
  int ex = block_exscan(c);
  if (i < NN) offs[i] = bo + ex;
}

// ---------------- CSR fill: slot = offs[d] + tile-prefix + rank --------------
__global__ __launch_bounds__(256) void fill_kernel(const int* __restrict__ row,
                                                   const int* __restrict__ col,
                                                   const int* __restrict__ rank,
                                                   const int* __restrict__ cnt4,
                                                   const float* __restrict__ dis,
                                                   const int* __restrict__ offs,
                                                   int2* __restrict__ csr) {
  int e = blockIdx.x * 256 + threadIdx.x;
  if (e < NE) {
    int d = col[e];
    int s = row[e];
    int t = s / NTILE;
    int4 c4 = *(const int4*)&cnt4[d * 4];
    int pre = (t > 0 ? c4.x : 0) + (t > 1 ? c4.y : 0) + (t > 2 ? c4.z : 0);
    int pos = offs[d] + pre + rank[e];
    csr[pos] = make_int2(s, __float_as_int(dis[s] * dis[d]));
  }
}

// ---------------- embedding GEMM: h0 = x @ W_emb^T + b, fp16 + fp8(perm) -----
__global__ __launch_bounds__(512) void emb_gemm(const float* __restrict__ Xf,
                                                const short* __restrict__ Whi,
                                                const short* __restrict__ Wlo,
                                                const float* __restrict__ bias,
                                                __half* __restrict__ hnew,
                                                unsigned char* __restrict__ h8) {
  __shared__ short Wh[WSLOT];  // 32 KB
  __shared__ short Wl[WSLOT];  // 32 KB
  int tid = threadIdx.x;
#pragma unroll
  for (int i = tid * 8; i < WSLOT; i += 512 * 8) {
    *(bf16x8*)&Wh[i] = *(const bf16x8*)(Whi + i);
    *(bf16x8*)&Wl[i] = *(const bf16x8*)(Wlo + i);
  }
  __syncthreads();

  int wave = tid >> 6, lane = tid & 63;
  int quad = lane >> 4, r16 = lane & 15;
  int m0 = blockIdx.x * 128 + wave * 16;
  if (m0 >= NN) return;  // NN % 16 == 0
  int mA = m0 + r16;

  f32x4 acc[8];
#pragma unroll
  for (int t = 0; t < 8; ++t) acc[t] = (f32x4){0.f, 0.f, 0.f, 0.f};

#pragma unroll
  for (int ks = 0; ks < 4; ++ks) {
    int klane = ks * 32 + quad * 8;
    const float* xr = Xf + (size_t)mA * NH + klane;
    float4 a0 = *(const float4*)xr;
    float4 a1 = *(const float4*)(xr + 4);
    float af[8] = {a0.x, a0.y, a0.z, a0.w, a1.x, a1.y, a1.z, a1.w};
    bf16x8 xhi, xlo;
#pragma unroll
    for (int j = 0; j < 8; ++j) {
      short h = f2bf(af[j]);
      xhi[j] = h;
      xlo[j] = f2bf(af[j] - bf2f(h));
    }
#pragma unroll
    for (int t = 0; t < 8; ++t) {
      int fidx = ((ks * 8 + t) * 64 + lane) << 3;
      bf16x8 whi = *(const bf16x8*)&Wh[fidx];
      bf16x8 wlo = *(const bf16x8*)&Wl[fidx];
      acc[t] = __builtin_amdgcn_mfma_f32_16x16x32_bf16(whi, xhi, acc[t], 0, 0, 0);
      acc[t] = __builtin_amdgcn_mfma_f32_16x16x32_bf16(whi, xlo, acc[t], 0, 0, 0);
      acc[t] = __builtin_amdgcn_mfma_f32_16x16x32_bf16(wlo, xhi, acc[t], 0, 0, 0);
    }
  }

  int m = m0 + r16;
  int cb = quad * 4;
#pragma unroll
  for (int t = 0; t < 8; ++t) {
    int ch = t * 16 + cb;
    float4 bb = *(const float4*)(bias + ch);
    float o0 = acc[t][0] + bb.x, o1 = acc[t][1] + bb.y;
    float o2 = acc[t][2] + bb.z, o3 = acc[t][3] + bb.w;
    __half2 p01 = __float22half2_rn(make_float2(o0, o1));
    __half2 p23 = __float22half2_rn(make_float2(o2, o3));
    *(uint2*)(hnew + (size_t)m * NH + ch) =
        make_uint2(*(unsigned*)&p01, *(unsigned*)&p23);
    int v = 0;
    v = __builtin_amdgcn_cvt_pk_fp8_f32(o0, o1, v, 0);
    v = __builtin_amdgcn_cvt_pk_fp8_f32(o2, o3, v, 1);
    ((unsigned*)(h8 + (size_t)m * NH))[pdw(t, quad)] = (unsigned)v;
  }
}

// ---------------- fused layer: gather (A_hat . h, fp8 trunk) -> registers ->
// split-bf16 MFMA (W in LDS) -> bias+relu+residual+LN epilogue.
// Gather walks the tile-grouped CSR (round-1 2-edge loop, 56 VGPR); source
// tiling keeps the instantaneous random working set L2-resident.
template <bool LAST>
__global__ __launch_bounds__(512) void layer_fused(
    const unsigned char* __restrict__ h8in, const short* __restrict__ Whi,
    const short* __restrict__ Wlo, const float* __restrict__ bias,
    const __half* __restrict__ hprev, const float* __restrict__ gamma,
    const float* __restrict__ beta, const float* __restrict__ Wout,
    const float* __restrict__ dis, const int* __restrict__ offs,
    const int* __restrict__ deg, const int2* __restrict__ csr,
    __half* __restrict__ hnew, unsigned char* __restrict__ h8out,
    float* __restrict__ nodeval) {
  __shared__ short Wh[WSLOT];  // 32 KB
  __shared__ short Wl[WSLOT];  // 32 KB
  int tid = threadIdx.x;
#pragma unroll
  for (int i = tid * 8; i < WSLOT; i += 512 * 8) {
    *(bf16x8*)&Wh[i] = *(const bf16x8*)(Whi + i);
    *(bf16x8*)&Wl[i] = *(const bf16x8*)(Wlo + i);
  }
  // no barrier yet: gather overlaps the LDS staging latency

  int wave = tid >> 6, lane = tid & 63;
  int quad = lane >> 4, r16 = lane & 15;
  int m0 = blockIdx.x * 128 + wave * 16;
  bool active = m0 < NN;        // wave-uniform; inactive waves still barrier
  int nd = active ? m0 + r16 : 0;

  float ag[4][8];
#pragma unroll
  for (int ks = 0; ks < 4; ++ks)
#pragma unroll
    for (int j = 0; j < 8; ++j) ag[ks][j] = 0.f;

  const char* rbase = (const char*)h8in + quad * 32;
  {  // self loop: weight dis[nd]^2
    float dii = dis[nd];
    const uint4* rp = (const uint4*)(rbase + (size_t)nd * NH);
    uint4 qa = rp[0], qb = rp[1];
    fp8row_fma(ag, qa, qb, dii * dii);
  }
  int s0 = offs[nd];
  int e = active ? deg[nd] : 0;
  int j = 0;
  for (; j + 2 <= e; j += 2) {
    int2 p0 = csr[s0 + j], p1 = csr[s0 + j + 1];
    const uint4* r0 = (const uint4*)(rbase + (size_t)p0.x * NH);
    const uint4* r1 = (const uint4*)(rbase + (size_t)p1.x * NH);
    uint4 a0 = r0[0], b0 = r0[1];
    uint4 a1 = r1[0], b1 = r1[1];
    fp8row_fma(ag, a0, b0, __int_as_float(p0.y));
    fp8row_fma(ag, a1, b1, __int_as_float(p1.y));
  }
  if (j < e) {
    int2 p0 = csr[s0 + j];
    const uint4* r0 = (const uint4*)(rbase + (size_t)p0.x * NH);
    uint4 a0 = r0[0], b0 = r0[1];
    fp8row_fma(ag, a0, b0, __int_as_float(p0.y));
  }

  __syncthreads();  // W staging complete; all waves participate

  if (!active) return;

  f32x4 acc[8];
#pragma unroll
  for (int t = 0; t < 8; ++t) acc[t] = (f32x4){0.f, 0.f, 0.f, 0.f};

#pragma unroll
  for (int ks = 0; ks < 4; ++ks) {
    bf16x8 xhi, xlo;
#pragma unroll
    for (int q = 0; q < 8; ++q) {
      short hh = f2bf(ag[ks][q]);
      xhi[q] = hh;
      xlo[q] = f2bf(ag[ks][q] - bf2f(hh));
    }
#pragma unroll
    for (int t = 0; t < 8; ++t) {
      int fidx = ((ks * 8 + t) * 64 + lane) << 3;
      bf16x8 whi = *(const bf16x8*)&Wh[fidx];
      bf16x8 wlo = *(const bf16x8*)&Wl[fidx];
      acc[t] = __builtin_amdgcn_mfma_f32_16x16x32_bf16(whi, xhi, acc[t], 0, 0, 0);
      acc[t] = __builtin_amdgcn_mfma_f32_16x16x32_bf16(whi, xlo, acc[t], 0, 0, 0);
      acc[t] = __builtin_amdgcn_mfma_f32_16x16x32_bf16(wlo, xhi, acc[t], 0, 0, 0);
    }
  }

  // ---- epilogue: lane owns node m = m0 + r16, channels ch = t*16 + quad*4 + r
  int m = m0 + r16;
  int cb = quad * 4;
  float vv[8][4];
  float s = 0.f, s2 = 0.f;
#pragma unroll
  for (int t = 0; t < 8; ++t) {
    int ch = t * 16 + cb;
    float4 bb = *(const float4*)(bias + ch);
    uint2 hp = *(const uint2*)(hprev + (size_t)m * NH + ch);
    float2 h01 = __half22float2(*(__half2*)&hp.x);
    float2 h23 = __half22float2(*(__half2*)&hp.y);
    float hv[4] = {h01.x, h01.y, h23.x, h23.y};
    float bb4[4] = {bb.x, bb.y, bb.z, bb.w};
#pragma unroll
    for (int r = 0; r < 4; ++r) {
      float z = fmaxf(acc[t][r] + bb4[r], 0.f);
      float val = hv[r] + z;
      vv[t][r] = val;
      s += val;
      s2 += val * val;
    }
  }
  // reduce across the 4 quads holding this node
  s += __shfl_xor(s, 16, 64);
  s += __shfl_xor(s, 32, 64);
  s2 += __shfl_xor(s2, 16, 64);
  s2 += __shfl_xor(s2, 32, 64);
  float mean = s * (1.f / 128.f);
  float var = fmaxf(s2 * (1.f / 128.f) - mean * mean, 0.f);
  float inv = rsqrtf(var + 1e-5f);
  float d = 0.f;
#pragma unroll
  for (int t = 0; t < 8; ++t) {
    int ch = t * 16 + cb;
    float4 gv = *(const float4*)(gamma + ch);
    float4 bt = *(const float4*)(beta + ch);
    float o0 = (vv[t][0] - mean) * inv * gv.x + bt.x;
    float o1 = (vv[t][1] - mean) * inv * gv.y + bt.y;
    float o2 = (vv[t][2] - mean) * inv * gv.z + bt.z;
    float o3 = (vv[t][3] - mean) * inv * gv.w + bt.w;
    if (!LAST) {
      __half2 p01 = __float22half2_rn(make_float2(o0, o1));
      __half2 p23 = __float22half2_rn(make_float2(o2, o3));
      *(uint2*)(hnew + (size_t)m * NH + ch) =
          make_uint2(*(unsigned*)&p01, *(unsigned*)&p23);
      int pv = 0;
      pv = __builtin_amdgcn_cvt_pk_fp8_f32(o0, o1, pv, 0);
      pv = __builtin_amdgcn_cvt_pk_fp8_f32(o2, o3, pv, 1);
      ((unsigned*)(h8out + (size_t)m * NH))[pdw(t, quad)] = (unsigned)pv;
    } else {
      // last layer: nothing reads h/h8 afterwards; only nodeval matters
      float4 wv = *(const float4*)(Wout + ch);
      d += o0 * wv.x + o1 * wv.y + o2 * wv.z + o3 * wv.w;
    }
  }
  if (LAST) {
    d += __shfl_xor(d, 16, 64);
    d += __shfl_xor(d, 32, 64);
    if (lane < 16) nodeval[m] = d;
  }
}

// ---------------- LDS-binned segment reduction + last-block finalize ----------
__global__ __launch_bounds__(256) void reduce_pool_kernel(
    const float* __restrict__ nodeval, const int* __restrict__ batch,
    float* __restrict__ gsum, int* __restrict__ gcnt, int* __restrict__ done,
    float* __restrict__ out) {
  __shared__ float bins[NG];
  __shared__ int cbins[NG];
  __shared__ int lastflag;
  int tid = threadIdx.x;
  if (tid < NG) {
    bins[tid] = 0.f;
    cbins[tid] = 0;
  }
  __syncthreads();
  int i = blockIdx.x * 256 + tid;
  if (i < NN) {
    int g = batch[i];
    atomicAdd(&bins[g], nodeval[i]);
    atomicAdd(&cbins[g], 1);
  }
  __syncthreads();
  if (tid < NG && cbins[tid]) {
    atomicAdd(&gsum[tid], bins[tid]);
    atomicAdd(&gcnt[tid], cbins[tid]);
  }
  __threadfence();
  if (tid == 0) lastflag = (atomicAdd(done, 1) == (int)gridDim.x - 1);
  __syncthreads();
  if (lastflag && tid < NG) {
    // atomic reads: guaranteed to observe all prior device-scope atomics
    float sv = atomicAdd(&gsum[tid], 0.f);
    int cv = atomicAdd(&gcnt[tid], 0);
    out[tid] = sv / fmaxf((float)cv, 1.0f);
  }
}

extern "C" void kernel_launch(void* const* d_in, const int* in_sizes, int n_in,
                              void* d_out, int out_size, void* d_ws, size_t ws_size,
                              hipStream_t stream) {
  const float* x = (const float*)d_in[0];
  const int* eidx = (const int*)d_in[1];
  const int* batch = (const int*)d_in[2];
  const float* W_emb = (const float*)d_in[3];
  const float* b_emb = (const float*)d_in[4];
  const float* W_layers = (const float*)d_in[5];
  const float* b_layers = (const float*)d_in[6];
  const float* ln_gamma = (const float*)d_in[7];
  const float* ln_beta = (const float*)d_in[8];
  const float* W_out = (const float*)d_in[9];
  float* out = (float*)d_out;

  char* ws = (char*)d_ws;
  unsigned char* h8a = (unsigned char*)ws; ws += (size_t)NN * NH;  // fp8 trunk A
  unsigned char* h8b = (unsigned char*)ws; ws += (size_t)NN * NH;  // fp8 trunk B
  __half* h = (__half*)ws;      ws += (size_t)NN * NH * 2;         // fp16 trunk
  short* Whi = (short*)ws;      ws += (size_t)5 * WSLOT * 2;
  short* Wlo = (short*)ws;      ws += (size_t)5 * WSLOT * 2;
  float* dis = (float*)ws;      ws += (size_t)NN * 4;
  int2* csr = (int2*)ws;        ws += (size_t)NE * 8;
  int* rank = (int*)ws;         ws += (size_t)NE * 4;
  int* offs = (int*)ws;         ws += (size_t)NN * 4;
  int* deg = (int*)ws;          ws += (size_t)NN * 4;
  float* nodeval = (float*)ws;  ws += (size_t)NN * 4;
  int* bsum = (int*)ws;         ws += (size_t)NB * 4;
  char* zero_base = ws;
  int* cnt4 = (int*)ws;         ws += (size_t)NN * 16;
  float* gsum = (float*)ws;     ws += (size_t)NG * 4;
  int* gcnt = (int*)ws;         ws += (size_t)NG * 4;
  int* done = (int*)ws;         ws += 64;
  size_t zero_bytes = (size_t)(ws - zero_base);
  hipMemsetAsync(zero_base, 0, zero_bytes, stream);

  const int* erow = eidx;        // edge_index[0] = sources
  const int* ecol = eidx + NE;   // edge_index[1] = targets

  prep_hist_kernel<<<PREPB + HISTB, 256, 0, stream>>>(W_emb, W_layers, Whi, Wlo,
                                                      erow, ecol, cnt4, rank);
  scan1_kernel<<<NB, 256, 0, stream>>>(cnt4, bsum, dis, deg);
  scan3b_kernel<<<NB, 256, 0, stream>>>(deg, bsum, offs);
  fill_kernel<<<HISTB, 256, 0, stream>>>(erow, ecol, rank, cnt4, dis, offs, csr);

  int gblk = (NN + 127) / 128;
  // embedding: h0 = x @ W_emb^T + b_emb  -> h (fp16) + h8a (fp8, permuted)
  emb_gemm<<<gblk, 512, 0, stream>>>(x, Whi, Wlo, b_emb, h, h8a);
  for (int l = 0; l < NL; ++l) {
    const short* wh = Whi + (size_t)(l + 1) * WSLOT;
    const short* wl = Wlo + (size_t)(l + 1) * WSLOT;
    const float* bl = b_layers + (size_t)l * NH;
    const float* gl = ln_gamma + (size_t)l * NH;
    const float* be = ln_beta + (size_t)l * NH;
    const unsigned char* hin = (l & 1) ? h8b : h8a;
    unsigned char* hout = (l & 1) ? h8a : h8b;
    if (l == NL - 1)
      layer_fused<true><<<gblk, 512, 0, stream>>>(
          hin, wh, wl, bl, h, gl, be, W_out, dis, offs, deg, csr, h, nullptr,
          nodeval);
    else
      layer_fused<false><<<gblk, 512, 0, stream>>>(
          hin, wh, wl, bl, h, gl, be, nullptr, dis, offs, deg, csr, h, hout,
          nullptr);
  }
  reduce_pool_kernel<<<NB, 256, 0, stream>>>(nodeval, batch, gsum, gcnt, done,
                                             out);
}